// Round 15
// baseline (177.149 us; speedup 1.0000x reference)
//
#include <hip/hip_runtime.h>
#include <hip/hip_fp16.h>

#define DAMPF 0.9998f

typedef float nfloat4 __attribute__((ext_vector_type(4)));  // native vec for nt builtins

constexpr int T_len = 8192;
constexpr int NCH   = 64;            // chunks per (b,m) group
constexpr int CHLEN = T_len / NCH;   // 128
constexpr int TT    = 32;            // staging tile t-extent (= one 128B line/row)
constexpr int NTILE = CHLEN / TT;    // 4
constexpr int SF    = TT + 1;        // 33: padded row stride, conflict-free reads

constexpr size_t VEL_BYTES    = (size_t)128 * T_len * 64 * 2;  // 128 MiB fp16 [bm][t/2][d][2]
constexpr size_t STATES_BYTES = (size_t)128 * NCH * 128 * 4;   // 4 MiB
constexpr size_t WS_NEEDED    = VEL_BYTES + STATES_BYTES;

// ---- pass 1 (R14, unchanged): zero-init chunk scan; NT F,H loads; fp16 vel ---
template<bool WV>
__global__ __launch_bounds__(128) void goo_pass1(
    const float* __restrict__ F, const float* __restrict__ H,
    const float* __restrict__ tens, const float* __restrict__ mass,
    float* __restrict__ states, uint32_t* __restrict__ vb)
{
  __shared__ float ftile[2][64*SF];
  __shared__ float htile[2][64*SF];
  const int widx = threadIdx.x >> 6;
  const int lane = threadIdx.x & 63;
  const int w    = blockIdx.x * 2 + widx;   // 0..8191
  const int bm   = w >> 6;
  const int c    = w & (NCH - 1);
  const int m    = bm & 63;
  const float k  = tens[m*64 + lane] / mass[m];

  float* ftw = ftile[widx];
  float* htw = htile[widx];
  const int r8 = lane >> 3;            // 0..7
  const int c4 = (lane & 7) * 4;       // 0..28
  const int la = r8*SF + c4;
  const size_t gbase = (size_t)bm * 64 * T_len + (size_t)c * CHLEN
                     + (size_t)r8 * T_len + c4;
  const float* Fp = F + gbase;
  const float* Hp = H + gbase;
  const int dbase = lane * SF;
  uint32_t* vstore = WV ? (vb + (((size_t)bm*(T_len/2) + (size_t)c*(CHLEN/2))*64 + lane))
                        : nullptr;

  nfloat4 pf[8], ph[8];
  auto load_tile = [&](int toff) {
    #pragma unroll
    for (int i = 0; i < 8; ++i) {
      pf[i] = __builtin_nontemporal_load(
                (const nfloat4*)(Fp + (size_t)(8*i) * T_len + toff));
      ph[i] = __builtin_nontemporal_load(
                (const nfloat4*)(Hp + (size_t)(8*i) * T_len + toff));
    }
  };
  auto store_tile = [&]() {
    #pragma unroll
    for (int i = 0; i < 8; ++i) {
      const int a = la + 8*i*SF;
      ftw[a+0]=pf[i].x; ftw[a+1]=pf[i].y; ftw[a+2]=pf[i].z; ftw[a+3]=pf[i].w;
      htw[a+0]=ph[i].x; htw[a+1]=ph[i].y; htw[a+2]=ph[i].z; htw[a+3]=ph[i].w;
    }
  };

  float pos = 0.f, vel = 0.f, prev = 0.f;
  load_tile(0);
  for (int tt = 0; tt < NTILE; ++tt) {
    store_tile();
    __builtin_amdgcn_wave_barrier();
    if (tt + 1 < NTILE) load_tile((tt+1)*TT);
    uint32_t* vtile = WV ? (vstore + (size_t)tt * 16 * 64) : nullptr;  // per-tile base
    #pragma unroll
    for (int t = 0; t < TT; ++t) {
      float ff = ftw[dbase + t];
      float hh = htw[dbase + t];
      float acc = fmaf(k, hh - pos, ff);
      vel = (vel + acc) * DAMPF;
      pos += vel;
      if (WV) {
        if (t & 1) {
          vtile[(t >> 1) * 64] =
            __builtin_bit_cast(uint32_t, __builtin_amdgcn_cvt_pkrtz(prev, vel));
        } else {
          prev = vel;
        }
      }
    }
    __builtin_amdgcn_wave_barrier();
  }
  const size_t slot = ((size_t)bm*NCH + c) * 128;
  states[slot + lane]      = pos;
  states[slot + 64 + lane] = vel;
}

// -------- pass 2 (fast, combine folded in): per-wave prefix x0, then scan -----
// Each thread rebuilds its chunk's initial state x0 = sum_{j<c} A^{L(c-1-j)} zf[j]
// via the serial prefix x = A^L x + zf[j] (f64, as the old combine). states is
// now READ-ONLY (no separate combine dispatch, no RMW hazard across replays).
__global__ __launch_bounds__(256) void goo_pass2_fast(
    const uint32_t* __restrict__ vb, const float* __restrict__ states,
    const float* __restrict__ mic, const float* __restrict__ mass,
    const float* __restrict__ tens, const float* __restrict__ gains,
    float* __restrict__ out)
{
  const int lane = threadIdx.x & 63;
  const int w    = blockIdx.x * 4 + (threadIdx.x >> 6);  // 0..8191
  const int bm   = w >> 6;
  const int c    = w & (NCH - 1);
  const int m    = bm & 63;
  const float k       = tens[m*64 + lane] / mass[m];
  const float Dk      = DAMPF * k;
  const float pregain = 2.0f * gains[m];
  const float micv    = mic[bm*64 + lane];
  const float m2n     = -2.0f * micv;

  // A^L (L=128) in double, 7 squarings — same arithmetic as the old combine.
  const double kd = (double)tens[m*64 + lane] / (double)mass[m];
  const double Dd = 0.9998;
  double a00 = 1.0 - Dd*kd, a01 = Dd, a10 = -Dd*kd, a11 = Dd;
  #pragma unroll
  for (int i = 0; i < 7; ++i) {
    double b00 = a00*a00 + a01*a10;
    double b01 = a00*a01 + a01*a11;
    double b10 = a10*a00 + a11*a10;
    double b11 = a10*a01 + a11*a11;
    a00=b00; a01=b01; a10=b10; a11=b11;
  }
  // serial prefix over earlier chunks (c iterations; loads L2/L3-hit, TLP-hidden)
  double xp = 0.0, xv = 0.0;
  for (int j = 0; j < c; ++j) {
    const size_t base = ((size_t)bm*NCH + j)*128 + lane;
    const double zp = (double)states[base];
    const double zv = (double)states[base + 64];
    const double np = a00*xp + a01*xv + zp;
    const double nv = a10*xp + a11*xv + zv;
    xp = np; xv = nv;
  }
  float wp = (float)xp;                    // x0 (pos)
  float wv = (float)xv;                    // x0 (vel)

  const uint32_t* vp = vb + (((size_t)bm*(T_len/2) + (size_t)c*(CHLEN/2))*64 + lane);
  const bool odd = lane & 1;

  for (int half = 0; half < 2; ++half) {
    float keep = 0.f;
    #pragma unroll 8
    for (int j = 0; j < 32; ++j) {
      const uint32_t pk = vp[(size_t)(half*32 + j) * 64];
      const __half2 h2 = __builtin_bit_cast(__half2, pk);
      const float2 vpair = __half22float2(h2);
      wv = fmaf(-Dk, wp, DAMPF*wv); wp += wv;
      const float va = vpair.x + wv;
      wv = fmaf(-Dk, wp, DAMPF*wv); wp += wv;
      const float vbv = vpair.y + wv;
      const float ya = fmaf(m2n, __builtin_amdgcn_rcpf(__expf(va *pregain) + 1.f), micv);
      const float yb = fmaf(m2n, __builtin_amdgcn_rcpf(__expf(vbv*pregain) + 1.f), micv);
      const float d0 = odd ? yb : ya;
      const float e0 = __shfl_xor(odd ? ya : yb, 1);
      float f = d0 + e0;
      f += __shfl_xor(f, 2);
      f += __shfl_xor(f, 4);
      f += __shfl_xor(f, 8);
      f += __shfl_xor(f, 16);
      f += __shfl_xor(f, 32);
      keep = (lane == 2*j + (int)odd) ? f : keep;
    }
    out[(size_t)bm*T_len + c*CHLEN + half*64 + lane] = keep;
  }
}

// -------- fallback path (small ws): combine + slow pass2 (R2 structure) -------
__global__ __launch_bounds__(256) void goo_combine(
    const float* __restrict__ tens, const float* __restrict__ mass,
    float* __restrict__ states)
{
  const int tid = blockIdx.x * 256 + threadIdx.x;  // 0..8191
  const int bm  = tid >> 6;
  const int d   = tid & 63;
  const int m   = bm & 63;
  const double k  = (double)tens[m*64 + d] / (double)mass[m];
  const double Dd = 0.9998;
  double a00 = 1.0 - Dd*k, a01 = Dd, a10 = -Dd*k, a11 = Dd;
  #pragma unroll
  for (int i = 0; i < 7; ++i) {
    double b00 = a00*a00 + a01*a10;
    double b01 = a00*a01 + a01*a11;
    double b10 = a10*a00 + a11*a10;
    double b11 = a10*a01 + a11*a11;
    a00=b00; a01=b01; a10=b10; a11=b11;
  }
  double xp = 0.0, xv = 0.0;
  for (int c = 0; c < NCH; ++c) {
    const size_t base = ((size_t)bm*NCH + c)*128 + d;
    const float zp = states[base];
    const float zv = states[base + 64];
    states[base]      = (float)xp;
    states[base + 64] = (float)xv;
    const double np = a00*xp + a01*xv + (double)zp;
    const double nv = a10*xp + a11*xv + (double)zv;
    xp = np; xv = nv;
  }
}

__global__ __launch_bounds__(128) void goo_pass2_slow(
    const float* __restrict__ F, const float* __restrict__ H,
    const float* __restrict__ mic, const float* __restrict__ mass,
    const float* __restrict__ tens, const float* __restrict__ gains,
    const float* __restrict__ states, float* __restrict__ out)
{
  __shared__ float ftile[2][64*SF];
  __shared__ float htile[2][64*SF];
  const int widx = threadIdx.x >> 6;
  const int lane = threadIdx.x & 63;
  const int w    = blockIdx.x * 2 + widx;
  const int bm   = w >> 6;
  const int c    = w & (NCH - 1);
  const int m    = bm & 63;
  const float k       = tens[m*64 + lane] / mass[m];
  const float pregain = 2.0f * gains[m];
  const float micv    = mic[bm*64 + lane];
  const float m2n     = -2.0f * micv;

  float* ftw = ftile[widx];
  float* htw = htile[widx];
  const int r8 = lane >> 3;
  const int c4 = (lane & 7) * 4;
  const int la = r8*SF + c4;
  const size_t gbase = (size_t)bm * 64 * T_len + (size_t)c * CHLEN
                     + (size_t)r8 * T_len + c4;
  const float* Fp = F + gbase;
  const float* Hp = H + gbase;
  const int dbase = lane * SF;

  float4 pf[8], ph[8];
  auto load_tile = [&](int toff) {
    #pragma unroll
    for (int i = 0; i < 8; ++i) {
      pf[i] = *(const float4*)(Fp + (size_t)(8*i) * T_len + toff);
      ph[i] = *(const float4*)(Hp + (size_t)(8*i) * T_len + toff);
    }
  };
  auto store_tile = [&]() {
    #pragma unroll
    for (int i = 0; i < 8; ++i) {
      const int a = la + 8*i*SF;
      ftw[a+0]=pf[i].x; ftw[a+1]=pf[i].y; ftw[a+2]=pf[i].z; ftw[a+3]=pf[i].w;
      htw[a+0]=ph[i].x; htw[a+1]=ph[i].y; htw[a+2]=ph[i].z; htw[a+3]=ph[i].w;
    }
  };

  const size_t slot = ((size_t)bm*NCH + c) * 128;
  float pos = states[slot + lane];
  float vel = states[slot + 64 + lane];

  float keep = 0.f;
  load_tile(0);
  for (int tt = 0; tt < NTILE; ++tt) {
    store_tile();
    __builtin_amdgcn_wave_barrier();
    if (tt + 1 < NTILE) load_tile((tt+1)*TT);
    #pragma unroll
    for (int t = 0; t < TT; ++t) {
      float ff = ftw[dbase + t];
      float hh = htw[dbase + t];
      float acc = fmaf(k, hh - pos, ff);
      vel = (vel + acc) * DAMPF;
      pos += vel;
      float e  = __expf(vel * pregain);
      float rr = __builtin_amdgcn_rcpf(e + 1.0f);
      float y  = fmaf(m2n, rr, micv);
      y += __shfl_xor(y, 1);
      y += __shfl_xor(y, 2);
      y += __shfl_xor(y, 4);
      y += __shfl_xor(y, 8);
      y += __shfl_xor(y, 16);
      y += __shfl_xor(y, 32);
      const int tmod = (tt & 1) * TT + t;
      keep = (lane == tmod) ? y : keep;
    }
    __builtin_amdgcn_wave_barrier();
    if (tt & 1) {
      out[(size_t)bm*T_len + c*CHLEN + (tt>>1)*64 + lane] = keep;
    }
  }
}

extern "C" void kernel_launch(void* const* d_in, const int* in_sizes, int n_in,
                              void* d_out, int out_size, void* d_ws, size_t ws_size,
                              hipStream_t stream)
{
  const float* F    = (const float*)d_in[0];  // forces   (B,M,D,T)
  const float* H    = (const float*)d_in[1];  // home_mod (B,M,D,T)
  const float* mic  = (const float*)d_in[2];  // (B,M,D,1)
  const float* mass = (const float*)d_in[3];  // (M,)
  const float* tens = (const float*)d_in[4];  // (M,D)
  const float* gain = (const float*)d_in[5];  // (M,)
  float* out = (float*)d_out;                 // (B,M,T,1) f32

  const bool fast = ws_size >= WS_NEEDED;
  if (fast) {
    uint32_t* vb   = (uint32_t*)d_ws;                       // 128 MiB fp16 vel^p
    float* states  = (float*)((char*)d_ws + VEL_BYTES);     // 4 MiB zf records
    goo_pass1<true><<<4096, 128, 0, stream>>>(F, H, tens, mass, states, vb);
    goo_pass2_fast <<<2048, 256, 0, stream>>>(vb, states, mic, mass, tens, gain, out);
  } else {
    float* states = (float*)d_ws;                           // 4 MiB states
    goo_pass1<false><<<4096, 128, 0, stream>>>(F, H, tens, mass, states, nullptr);
    goo_combine   <<<  32, 256, 0, stream>>>(tens, mass, states);
    goo_pass2_slow<<<4096, 128, 0, stream>>>(F, H, mic, mass, tens, gain, states, out);
  }
}

// Round 16
// 165.590 us; speedup vs baseline: 1.0698x; 1.0698x over previous
//
#include <hip/hip_runtime.h>
#include <hip/hip_fp16.h>

#define DAMPF 0.9998f

typedef float nfloat4 __attribute__((ext_vector_type(4)));  // native vec for nt builtins

constexpr int T_len = 8192;
constexpr int NCH   = 64;            // chunks per (b,m) group
constexpr int CHLEN = T_len / NCH;   // 128
constexpr int TT    = 32;            // staging tile t-extent (= one 128B line/row)
constexpr int NTILE = CHLEN / TT;    // 4
constexpr int SF    = TT + 1;        // 33: padded row stride, conflict-free reads

constexpr size_t VEL_BYTES    = (size_t)128 * T_len * 64 * 2;  // 128 MiB fp16 [bm][t/2][d][2]
constexpr size_t STATES_BYTES = (size_t)128 * NCH * 128 * 4;   // 4 MiB
constexpr size_t WS_NEEDED    = VEL_BYTES + STATES_BYTES;

// ---- pass 1 (R14 config): zero-init chunk scan; NT F,H loads; fp16 vel out ---
template<bool WV>
__global__ __launch_bounds__(128) void goo_pass1(
    const float* __restrict__ F, const float* __restrict__ H,
    const float* __restrict__ tens, const float* __restrict__ mass,
    float* __restrict__ states, uint32_t* __restrict__ vb)
{
  __shared__ float ftile[2][64*SF];
  __shared__ float htile[2][64*SF];
  const int widx = threadIdx.x >> 6;
  const int lane = threadIdx.x & 63;
  const int w    = blockIdx.x * 2 + widx;   // 0..8191
  const int bm   = w >> 6;
  const int c    = w & (NCH - 1);
  const int m    = bm & 63;
  const float k  = tens[m*64 + lane] / mass[m];

  float* ftw = ftile[widx];
  float* htw = htile[widx];
  const int r8 = lane >> 3;            // 0..7
  const int c4 = (lane & 7) * 4;       // 0..28
  const int la = r8*SF + c4;
  const size_t gbase = (size_t)bm * 64 * T_len + (size_t)c * CHLEN
                     + (size_t)r8 * T_len + c4;
  const float* Fp = F + gbase;
  const float* Hp = H + gbase;
  const int dbase = lane * SF;
  uint32_t* vstore = WV ? (vb + (((size_t)bm*(T_len/2) + (size_t)c*(CHLEN/2))*64 + lane))
                        : nullptr;

  nfloat4 pf[8], ph[8];
  auto load_tile = [&](int toff) {
    #pragma unroll
    for (int i = 0; i < 8; ++i) {
      pf[i] = __builtin_nontemporal_load(
                (const nfloat4*)(Fp + (size_t)(8*i) * T_len + toff));
      ph[i] = __builtin_nontemporal_load(
                (const nfloat4*)(Hp + (size_t)(8*i) * T_len + toff));
    }
  };
  auto store_tile = [&]() {
    #pragma unroll
    for (int i = 0; i < 8; ++i) {
      const int a = la + 8*i*SF;
      ftw[a+0]=pf[i].x; ftw[a+1]=pf[i].y; ftw[a+2]=pf[i].z; ftw[a+3]=pf[i].w;
      htw[a+0]=ph[i].x; htw[a+1]=ph[i].y; htw[a+2]=ph[i].z; htw[a+3]=ph[i].w;
    }
  };

  float pos = 0.f, vel = 0.f, prev = 0.f;
  load_tile(0);
  for (int tt = 0; tt < NTILE; ++tt) {
    store_tile();
    __builtin_amdgcn_wave_barrier();
    if (tt + 1 < NTILE) load_tile((tt+1)*TT);
    uint32_t* vtile = WV ? (vstore + (size_t)tt * 16 * 64) : nullptr;  // per-tile base
    #pragma unroll
    for (int t = 0; t < TT; ++t) {
      float ff = ftw[dbase + t];
      float hh = htw[dbase + t];
      float acc = fmaf(k, hh - pos, ff);
      vel = (vel + acc) * DAMPF;
      pos += vel;
      if (WV) {
        if (t & 1) {
          // one v_cvt_pkrtz_f16_f32 + one global_store_dword (imm offset (t>>1)*256B)
          vtile[(t >> 1) * 64] =
            __builtin_bit_cast(uint32_t, __builtin_amdgcn_cvt_pkrtz(prev, vel));
        } else {
          prev = vel;
        }
      }
    }
    __builtin_amdgcn_wave_barrier();
  }
  const size_t slot = ((size_t)bm*NCH + c) * 128;
  states[slot + lane]      = pos;
  states[slot + 64 + lane] = vel;
}

// ---------------- combine: x0[c] = A^L x0[c-1] + zf[c-1], in place ------------
__global__ __launch_bounds__(256) void goo_combine(
    const float* __restrict__ tens, const float* __restrict__ mass,
    float* __restrict__ states)
{
  const int tid = blockIdx.x * 256 + threadIdx.x;  // 0..8191
  const int bm  = tid >> 6;
  const int d   = tid & 63;
  const int m   = bm & 63;
  const double k  = (double)tens[m*64 + d] / (double)mass[m];
  const double Dd = 0.9998;
  double a00 = 1.0 - Dd*k, a01 = Dd, a10 = -Dd*k, a11 = Dd;
  #pragma unroll
  for (int i = 0; i < 7; ++i) {      // A^(2^7) = A^128
    double b00 = a00*a00 + a01*a10;
    double b01 = a00*a01 + a01*a11;
    double b10 = a10*a00 + a11*a10;
    double b11 = a10*a01 + a11*a11;
    a00=b00; a01=b01; a10=b10; a11=b11;
  }
  double xp = 0.0, xv = 0.0;
  for (int c = 0; c < NCH; ++c) {
    const size_t base = ((size_t)bm*NCH + c)*128 + d;
    const float zp = states[base];
    const float zv = states[base + 64];
    states[base]      = (float)xp;   // overwrite zf slot with x0
    states[base + 64] = (float)xv;
    const double np = a00*xp + a01*xv + (double)zp;
    const double nv = a10*xp + a11*xv + (double)zv;
    xp = np; xv = nv;
  }
}

// -------- pass 2 (fast): vel = vel^p + [A^i x0]_v, tanh-reduce, write out -----
__global__ __launch_bounds__(256) void goo_pass2_fast(
    const uint32_t* __restrict__ vb, const float* __restrict__ states,
    const float* __restrict__ mic, const float* __restrict__ mass,
    const float* __restrict__ tens, const float* __restrict__ gains,
    float* __restrict__ out)
{
  const int lane = threadIdx.x & 63;
  const int w    = blockIdx.x * 4 + (threadIdx.x >> 6);  // 0..8191
  const int bm   = w >> 6;
  const int c    = w & (NCH - 1);
  const int m    = bm & 63;
  const float k       = tens[m*64 + lane] / mass[m];
  const float Dk      = DAMPF * k;
  const float pregain = 2.0f * gains[m];
  const float micv    = mic[bm*64 + lane];
  const float m2n     = -2.0f * micv;

  const size_t slot = ((size_t)bm*NCH + c) * 128;
  float wp = states[slot + lane];          // x0 (pos)
  float wv = states[slot + 64 + lane];     // x0 (vel)
  const uint32_t* vp = vb + (((size_t)bm*(T_len/2) + (size_t)c*(CHLEN/2))*64 + lane);
  const bool odd = lane & 1;

  for (int half = 0; half < 2; ++half) {
    float keep = 0.f;
    #pragma unroll 8
    for (int j = 0; j < 32; ++j) {
      const uint32_t pk = vp[(size_t)(half*32 + j) * 64];
      const __half2 h2 = __builtin_bit_cast(__half2, pk);
      const float2 vpair = __half22float2(h2);
      wv = fmaf(-Dk, wp, DAMPF*wv); wp += wv;
      const float va = vpair.x + wv;
      wv = fmaf(-Dk, wp, DAMPF*wv); wp += wv;
      const float vbv = vpair.y + wv;
      const float ya = fmaf(m2n, __builtin_amdgcn_rcpf(__expf(va *pregain) + 1.f), micv);
      const float yb = fmaf(m2n, __builtin_amdgcn_rcpf(__expf(vbv*pregain) + 1.f), micv);
      const float d0 = odd ? yb : ya;
      const float e0 = __shfl_xor(odd ? ya : yb, 1);
      float f = d0 + e0;
      f += __shfl_xor(f, 2);
      f += __shfl_xor(f, 4);
      f += __shfl_xor(f, 8);
      f += __shfl_xor(f, 16);
      f += __shfl_xor(f, 32);
      keep = (lane == 2*j + (int)odd) ? f : keep;
    }
    out[(size_t)bm*T_len + c*CHLEN + half*64 + lane] = keep;
  }
}

// -------- pass 2 (fallback, R2 version): re-reads F,H -------------------------
__global__ __launch_bounds__(128) void goo_pass2_slow(
    const float* __restrict__ F, const float* __restrict__ H,
    const float* __restrict__ mic, const float* __restrict__ mass,
    const float* __restrict__ tens, const float* __restrict__ gains,
    const float* __restrict__ states, float* __restrict__ out)
{
  __shared__ float ftile[2][64*SF];
  __shared__ float htile[2][64*SF];
  const int widx = threadIdx.x >> 6;
  const int lane = threadIdx.x & 63;
  const int w    = blockIdx.x * 2 + widx;
  const int bm   = w >> 6;
  const int c    = w & (NCH - 1);
  const int m    = bm & 63;
  const float k       = tens[m*64 + lane] / mass[m];
  const float pregain = 2.0f * gains[m];
  const float micv    = mic[bm*64 + lane];
  const float m2n     = -2.0f * micv;

  float* ftw = ftile[widx];
  float* htw = htile[widx];
  const int r8 = lane >> 3;
  const int c4 = (lane & 7) * 4;
  const int la = r8*SF + c4;
  const size_t gbase = (size_t)bm * 64 * T_len + (size_t)c * CHLEN
                     + (size_t)r8 * T_len + c4;
  const float* Fp = F + gbase;
  const float* Hp = H + gbase;
  const int dbase = lane * SF;

  float4 pf[8], ph[8];
  auto load_tile = [&](int toff) {
    #pragma unroll
    for (int i = 0; i < 8; ++i) {
      pf[i] = *(const float4*)(Fp + (size_t)(8*i) * T_len + toff);
      ph[i] = *(const float4*)(Hp + (size_t)(8*i) * T_len + toff);
    }
  };
  auto store_tile = [&]() {
    #pragma unroll
    for (int i = 0; i < 8; ++i) {
      const int a = la + 8*i*SF;
      ftw[a+0]=pf[i].x; ftw[a+1]=pf[i].y; ftw[a+2]=pf[i].z; ftw[a+3]=pf[i].w;
      htw[a+0]=ph[i].x; htw[a+1]=ph[i].y; htw[a+2]=ph[i].z; htw[a+3]=ph[i].w;
    }
  };

  const size_t slot = ((size_t)bm*NCH + c) * 128;
  float pos = states[slot + lane];
  float vel = states[slot + 64 + lane];

  float keep = 0.f;
  load_tile(0);
  for (int tt = 0; tt < NTILE; ++tt) {
    store_tile();
    __builtin_amdgcn_wave_barrier();
    if (tt + 1 < NTILE) load_tile((tt+1)*TT);
    #pragma unroll
    for (int t = 0; t < TT; ++t) {
      float ff = ftw[dbase + t];
      float hh = htw[dbase + t];
      float acc = fmaf(k, hh - pos, ff);
      vel = (vel + acc) * DAMPF;
      pos += vel;
      float e  = __expf(vel * pregain);
      float rr = __builtin_amdgcn_rcpf(e + 1.0f);
      float y  = fmaf(m2n, rr, micv);
      y += __shfl_xor(y, 1);
      y += __shfl_xor(y, 2);
      y += __shfl_xor(y, 4);
      y += __shfl_xor(y, 8);
      y += __shfl_xor(y, 16);
      y += __shfl_xor(y, 32);
      const int tmod = (tt & 1) * TT + t;
      keep = (lane == tmod) ? y : keep;
    }
    __builtin_amdgcn_wave_barrier();
    if (tt & 1) {
      out[(size_t)bm*T_len + c*CHLEN + (tt>>1)*64 + lane] = keep;
    }
  }
}

extern "C" void kernel_launch(void* const* d_in, const int* in_sizes, int n_in,
                              void* d_out, int out_size, void* d_ws, size_t ws_size,
                              hipStream_t stream)
{
  const float* F    = (const float*)d_in[0];  // forces   (B,M,D,T)
  const float* H    = (const float*)d_in[1];  // home_mod (B,M,D,T)
  const float* mic  = (const float*)d_in[2];  // (B,M,D,1)
  const float* mass = (const float*)d_in[3];  // (M,)
  const float* tens = (const float*)d_in[4];  // (M,D)
  const float* gain = (const float*)d_in[5];  // (M,)
  float* out = (float*)d_out;                 // (B,M,T,1) f32

  const bool fast = ws_size >= WS_NEEDED;
  if (fast) {
    uint32_t* vb   = (uint32_t*)d_ws;                       // 128 MiB fp16 vel^p
    float* states  = (float*)((char*)d_ws + VEL_BYTES);     // 4 MiB states
    goo_pass1<true><<<4096, 128, 0, stream>>>(F, H, tens, mass, states, vb);
    goo_combine   <<<  32, 256, 0, stream>>>(tens, mass, states);
    goo_pass2_fast<<<2048, 256, 0, stream>>>(vb, states, mic, mass, tens, gain, out);
  } else {
    float* states = (float*)d_ws;                           // 4 MiB states
    goo_pass1<false><<<4096, 128, 0, stream>>>(F, H, tens, mass, states, nullptr);
    goo_combine   <<<  32, 256, 0, stream>>>(tens, mass, states);
    goo_pass2_slow<<<4096, 128, 0, stream>>>(F, H, mic, mass, tens, gain, states, out);
  }
}